// Round 3
// baseline (146.382 us; speedup 1.0000x reference)
//
#include <hip/hip_runtime.h>
#include <hip/hip_bf16.h>

// ProbabilisticMap: out[b][x][y][t] = scale(b,t) * exp(-0.5 * d^T inv(cov(b,t)) d),
// d = (x,y) - mean(b,t); mean/cov are Bernstein-weighted sums over <=8 control pts.
//
// Round 5: R2's float4/4-row map REGRESSED (141.7 -> 145.1): store width is not
// the limiter. Revised model: the whole iteration is pinned by total HBM WRITE
// traffic -- harness poison fill (512 MiB, partially parked dirty in L3 and
// drained during our window) + out (128 MiB) = 640 MiB at ~4.7 TB/s sustained
// write rate => ~136 us floor. This round: revert map to the proven R1 scalar
// structure (141.7 us) and make output stores NONTEMPORAL so map's stream does
// not displace dirty poison lines in L2/L3 (reduces cache churn in the shared
// drain; bytes unchanged). If this lands ~137-141 us we are at the write wall.
//
// Layouts (C-order):
//   cp_means: (K=8, B=128, 2)     fp32 (or bf16 -- detected)
//   num_cps : (B=128,)            int32 (or int64 -- detected)
//   cp_cov  : (K=8, B=128, 2, 2)  fp32 (or bf16 -- detected)
//   out     : (B=128, W=64, H=64, T=64) fp32  -> 128 MiB
//   ws      : (B=128, T=64, 8) fp32 = 256 KiB  {mx,my,g00,gxy,g11,sc,0,0}

#define MAP_W 64
#define MAP_H 64
#define T_SIZE 64
#define NUM_CP 8
#define BATCH 128
#define STATS_F 8   // floats per (b,t) stat record (padded to 32 B)

// Per-(b,t) Bernstein-weighted mean/cov -> folded inverse + scale.
// Numerics identical (same ops, same order) to the verified round-2 kernel.
__device__ __forceinline__ void bezier_stats(
    const void* __restrict__ cp_means_p,
    const void* __restrict__ num_cps_p,
    const void* __restrict__ cp_cov_p,
    const int b, const int t_i,
    float& mx_o, float& my_o, float& g00_o, float& gxy_o, float& g11_o, float& sc_o)
{
    // ---- runtime dtype detection (wave-uniform, deterministic) ----
    const int* ni32 = (const int*)num_cps_p;
    const bool is_i64 = (ni32[1] == 0);              // values 3..8, never 0
    const int  ncp = is_i64 ? (int)((const long long*)num_cps_p)[b] : ni32[b];
    const int  n   = ncp - 1;                        // 2..7

    const __hip_bfloat16* mbv = (const __hip_bfloat16*)cp_means_p;
    const __hip_bfloat16* cbv = (const __hip_bfloat16*)cp_cov_p;
    const float*          mf  = (const float*)cp_means_p;
    const float*          cf  = (const float*)cp_cov_p;
    // means are in [0,63]; fp32 data viewed as bf16 has random low-halves
    bool is_f32 = false;
    #pragma unroll
    for (int i = 0; i < 32; ++i) {
        const float v = __bfloat162float(mbv[i]);
        if (!(v >= 0.0f && v <= 64.0f)) is_f32 = true;   // NaN lands here too
    }

    // t = linspace(0,1,64)[t_i]
    const float t   = (float)t_i * (1.0f / 63.0f);
    const float omt = 1.0f - t;

    float mx = 0.f, my = 0.f, ca = 0.f, cb = 0.f, cc = 0.f, cd = 0.f;
    float ck = 1.0f, tk = 1.0f;
    #pragma unroll
    for (int k = 0; k < NUM_CP; ++k) {
        const int e = n - k;
        float onk = (e == 0) ? 1.0f : 0.0f;
        float o = 1.0f;
        #pragma unroll
        for (int j = 1; j < NUM_CP; ++j) { o *= omt; if (e == j) onk = o; }
        const float w  = (k <= n) ? ck * tk * onk : 0.0f;
        const float w2 = w * w;
        const int base = k * BATCH + b;
        const float m0 = is_f32 ? mf[base*2+0] : __bfloat162float(mbv[base*2+0]);
        const float m1 = is_f32 ? mf[base*2+1] : __bfloat162float(mbv[base*2+1]);
        const float q0 = is_f32 ? cf[base*4+0] : __bfloat162float(cbv[base*4+0]);
        const float q1 = is_f32 ? cf[base*4+1] : __bfloat162float(cbv[base*4+1]);
        const float q2 = is_f32 ? cf[base*4+2] : __bfloat162float(cbv[base*4+2]);
        const float q3 = is_f32 ? cf[base*4+3] : __bfloat162float(cbv[base*4+3]);
        mx = fmaf(w,  m0, mx);
        my = fmaf(w,  m1, my);
        ca = fmaf(w2, q0, ca);
        cb = fmaf(w2, q1, cb);
        cc = fmaf(w2, q2, cc);
        cd = fmaf(w2, q3, cd);
        ck = ck * (float)(n - k) / (float)(k + 1);
        tk *= t;
    }

    // 2x2 inverse folded with -0.5*log2(e) -> inner loop uses native exp2
    const float det     = fmaf(ca, cd, -(cb * cc));  // > 0
    const float inv_det = 1.0f / det;
    const float HL2E    = 0.72134752044448170368f;   // 0.5 * log2(e)
    mx_o  = mx;
    my_o  = my;
    g00_o = -HL2E * cd * inv_det;
    gxy_o =  HL2E * (cb + cc) * inv_det;
    g11_o = -HL2E * ca * inv_det;
    sc_o  = 0.15915494309189535f / sqrtf(det);       // 1/(2*pi*sqrt(det))
}

// ---- kernel 1: stats. 8192 threads = 32 blocks x 256. gid = b*64 + t. ----
__global__ __launch_bounds__(256) void stats_kernel(
    const void* __restrict__ cp_means_p,
    const void* __restrict__ num_cps_p,
    const void* __restrict__ cp_cov_p,
    float* __restrict__ ws)
{
    const int gid = blockIdx.x * 256 + threadIdx.x;  // (b<<6) | t
    const int b   = gid >> 6;
    const int t_i = gid & 63;

    float mx, my, g00, gxy, g11, sc;
    bezier_stats(cp_means_p, num_cps_p, cp_cov_p, b, t_i, mx, my, g00, gxy, g11, sc);

    float4* w4 = (float4*)(ws + (size_t)gid * STATS_F);
    w4[0] = make_float4(mx, my, g00, gxy);
    w4[1] = make_float4(g11, sc, 0.0f, 0.0f);
}

// ---- kernel 2: map. One block per (b,x); scalar NT write stream (R1 base). --
__global__ __launch_bounds__(256) void map_kernel(
    const float* __restrict__ ws,
    float* __restrict__ out)
{
    const int tid = threadIdx.x;
    const int blk = blockIdx.x;        // blk = b*64 + x
    const int b   = blk >> 6;
    const int x   = blk & 63;

    const int t_idx = tid & 63;
    const int y0    = tid >> 6;        // 0..3

    // wave reads 2 KiB contiguous (L1/L2-resident: 256 KiB total stats)
    const float4* s4 = (const float4*)(ws + ((size_t)((b << 6) | t_idx)) * STATS_F);
    const float4 s0 = s4[0];
    const float4 s1 = s4[1];
    const float mx = s0.x, my = s0.y, g00 = s0.z, gxy = s0.w;
    const float g11 = s1.x, sc = s1.y;

    // fold block-uniform x (same expression order as the verified kernel)
    const float dx = (float)x - mx;
    const float c0 = g00 * dx * dx;
    const float c1 = gxy * dx;

    float* __restrict__ orow = out + ((size_t)blk << 12) + t_idx;

    #pragma unroll
    for (int y = y0; y < MAP_H; y += 4) {
        const float dy  = (float)y - my;
        const float arg = fmaf(dy, fmaf(g11, dy, c1), c0);  // log2-domain quad form
        // nontemporal: don't displace dirty poison lines in L2/L3 -- the
        // iteration is pinned by total HBM write drain (fill 512 MiB + 128 MiB)
        __builtin_nontemporal_store(sc * exp2f(arg), &orow[y << 6]);
    }
}

// ---- fallback: verified single kernel (used if ws too small) ----
__global__ __launch_bounds__(256) void pmap_kernel(
    const void* __restrict__ cp_means_p,
    const void* __restrict__ num_cps_p,
    const void* __restrict__ cp_cov_p,
    float* __restrict__ out)
{
    __shared__ float s_my[T_SIZE], s_g11[T_SIZE], s_c0[T_SIZE], s_c1[T_SIZE], s_sc[T_SIZE];

    const int tid = threadIdx.x;
    const int blk = blockIdx.x;        // blk = b*64 + x
    const int b   = blk >> 6;
    const int x   = blk & 63;

    if (tid < T_SIZE) {
        float mx, my, g00, gxy, g11, sc;
        bezier_stats(cp_means_p, num_cps_p, cp_cov_p, b, tid, mx, my, g00, gxy, g11, sc);
        const float dx = (float)x - mx;
        s_my[tid]  = my;
        s_g11[tid] = g11;
        s_c0[tid]  = g00 * dx * dx;
        s_c1[tid]  = gxy * dx;
        s_sc[tid]  = sc;
    }
    __syncthreads();

    const int t_idx = tid & 63;
    const int y0    = tid >> 6;
    const float my  = s_my[t_idx];
    const float g11 = s_g11[t_idx];
    const float c0  = s_c0[t_idx];
    const float c1  = s_c1[t_idx];
    const float sc  = s_sc[t_idx];

    float* __restrict__ orow = out + ((size_t)blk << 12) + t_idx;

    #pragma unroll
    for (int y = y0; y < MAP_H; y += 4) {
        const float dy  = (float)y - my;
        const float arg = fmaf(dy, fmaf(g11, dy, c1), c0);
        orow[y << 6] = sc * exp2f(arg);
    }
}

extern "C" void kernel_launch(void* const* d_in, const int* in_sizes, int n_in,
                              void* d_out, int out_size, void* d_ws, size_t ws_size,
                              hipStream_t stream) {
    const size_t ws_needed = (size_t)BATCH * T_SIZE * STATS_F * sizeof(float); // 256 KiB
    if (d_ws != nullptr && ws_size >= ws_needed) {
        stats_kernel<<<dim3((BATCH * T_SIZE) / 256), dim3(256), 0, stream>>>(
            d_in[0], d_in[1], d_in[2], (float*)d_ws);
        map_kernel<<<dim3(BATCH * MAP_W), dim3(256), 0, stream>>>(
            (const float*)d_ws, (float*)d_out);
    } else {
        pmap_kernel<<<dim3(BATCH * MAP_W), dim3(256), 0, stream>>>(
            d_in[0], d_in[1], d_in[2], (float*)d_out);
    }
}

// Round 5
// 141.580 us; speedup vs baseline: 1.0339x; 1.0339x over previous
//
#include <hip/hip_runtime.h>
#include <hip/hip_bf16.h>

// ProbabilisticMap: out[b][x][y][t] = scale(b,t) * exp(-0.5 * d^T inv(cov(b,t)) d),
// d = (x,y) - mean(b,t); mean/cov are Bernstein-weighted sums over <=8 control pts.
//
// FINAL: round-4/R1 split-kernel structure -- the best harness-verified
// configuration (141.7 us). (Round-4 submission of this exact source hit an
// infra failure "container failed twice"; resubmitting unchanged.)
// Findings from the optimization ladder:
//   - single kernel (R0): 171.5 us -- phase-1 stats recomputed per (b,x) block
//     behind a barrier, 64x redundant; split into stats+map fixed it (-30 us).
//   - float4 stores + 4-row blocks (R2): NEUTRAL (store-issue width not limit)
//   - nontemporal stores (R3): NEUTRAL-to-negative
//   - our portion (stats+map) is pinned at ~60 us across all structures.
// Model: iteration is bound by total HBM WRITE drain: 512 MiB harness poison
// fill + 128 MiB output = 640 MiB at ~4.7 TB/s sustained write => ~136 us
// floor; measured 141.7 us = floor + stats (~4 us) + 2 launch overheads.
// This is the iteration-wide write roofline; no kernel restructure can cut
// bytes (output is mandatory, fill is harness-fixed).
//
// Layouts (C-order):
//   cp_means: (K=8, B=128, 2)     fp32 (or bf16 -- detected)
//   num_cps : (B=128,)            int32 (or int64 -- detected)
//   cp_cov  : (K=8, B=128, 2, 2)  fp32 (or bf16 -- detected)
//   out     : (B=128, W=64, H=64, T=64) fp32  -> 128 MiB
//   ws      : (B=128, T=64, 8) fp32 = 256 KiB  {mx,my,g00,gxy,g11,sc,0,0}

#define MAP_W 64
#define MAP_H 64
#define T_SIZE 64
#define NUM_CP 8
#define BATCH 128
#define STATS_F 8   // floats per (b,t) stat record (padded to 32 B)

// Per-(b,t) Bernstein-weighted mean/cov -> folded inverse + scale.
// Numerics identical (same ops, same order) to the original verified kernel.
__device__ __forceinline__ void bezier_stats(
    const void* __restrict__ cp_means_p,
    const void* __restrict__ num_cps_p,
    const void* __restrict__ cp_cov_p,
    const int b, const int t_i,
    float& mx_o, float& my_o, float& g00_o, float& gxy_o, float& g11_o, float& sc_o)
{
    // ---- runtime dtype detection (wave-uniform, deterministic) ----
    const int* ni32 = (const int*)num_cps_p;
    const bool is_i64 = (ni32[1] == 0);              // values 3..8, never 0
    const int  ncp = is_i64 ? (int)((const long long*)num_cps_p)[b] : ni32[b];
    const int  n   = ncp - 1;                        // 2..7

    const __hip_bfloat16* mbv = (const __hip_bfloat16*)cp_means_p;
    const __hip_bfloat16* cbv = (const __hip_bfloat16*)cp_cov_p;
    const float*          mf  = (const float*)cp_means_p;
    const float*          cf  = (const float*)cp_cov_p;
    // means are in [0,63]; fp32 data viewed as bf16 has random low-halves
    bool is_f32 = false;
    #pragma unroll
    for (int i = 0; i < 32; ++i) {
        const float v = __bfloat162float(mbv[i]);
        if (!(v >= 0.0f && v <= 64.0f)) is_f32 = true;   // NaN lands here too
    }

    // t = linspace(0,1,64)[t_i]
    const float t   = (float)t_i * (1.0f / 63.0f);
    const float omt = 1.0f - t;

    float mx = 0.f, my = 0.f, ca = 0.f, cb = 0.f, cc = 0.f, cd = 0.f;
    float ck = 1.0f, tk = 1.0f;
    #pragma unroll
    for (int k = 0; k < NUM_CP; ++k) {
        const int e = n - k;
        float onk = (e == 0) ? 1.0f : 0.0f;
        float o = 1.0f;
        #pragma unroll
        for (int j = 1; j < NUM_CP; ++j) { o *= omt; if (e == j) onk = o; }
        const float w  = (k <= n) ? ck * tk * onk : 0.0f;
        const float w2 = w * w;
        const int base = k * BATCH + b;
        const float m0 = is_f32 ? mf[base*2+0] : __bfloat162float(mbv[base*2+0]);
        const float m1 = is_f32 ? mf[base*2+1] : __bfloat162float(mbv[base*2+1]);
        const float q0 = is_f32 ? cf[base*4+0] : __bfloat162float(cbv[base*4+0]);
        const float q1 = is_f32 ? cf[base*4+1] : __bfloat162float(cbv[base*4+1]);
        const float q2 = is_f32 ? cf[base*4+2] : __bfloat162float(cbv[base*4+2]);
        const float q3 = is_f32 ? cf[base*4+3] : __bfloat162float(cbv[base*4+3]);
        mx = fmaf(w,  m0, mx);
        my = fmaf(w,  m1, my);
        ca = fmaf(w2, q0, ca);
        cb = fmaf(w2, q1, cb);
        cc = fmaf(w2, q2, cc);
        cd = fmaf(w2, q3, cd);
        ck = ck * (float)(n - k) / (float)(k + 1);
        tk *= t;
    }

    // 2x2 inverse folded with -0.5*log2(e) -> inner loop uses native exp2
    const float det     = fmaf(ca, cd, -(cb * cc));  // > 0
    const float inv_det = 1.0f / det;
    const float HL2E    = 0.72134752044448170368f;   // 0.5 * log2(e)
    mx_o  = mx;
    my_o  = my;
    g00_o = -HL2E * cd * inv_det;
    gxy_o =  HL2E * (cb + cc) * inv_det;
    g11_o = -HL2E * ca * inv_det;
    sc_o  = 0.15915494309189535f / sqrtf(det);       // 1/(2*pi*sqrt(det))
}

// ---- kernel 1: stats. 8192 threads = 32 blocks x 256. gid = b*64 + t. ----
__global__ __launch_bounds__(256) void stats_kernel(
    const void* __restrict__ cp_means_p,
    const void* __restrict__ num_cps_p,
    const void* __restrict__ cp_cov_p,
    float* __restrict__ ws)
{
    const int gid = blockIdx.x * 256 + threadIdx.x;  // (b<<6) | t
    const int b   = gid >> 6;
    const int t_i = gid & 63;

    float mx, my, g00, gxy, g11, sc;
    bezier_stats(cp_means_p, num_cps_p, cp_cov_p, b, t_i, mx, my, g00, gxy, g11, sc);

    float4* w4 = (float4*)(ws + (size_t)gid * STATS_F);
    w4[0] = make_float4(mx, my, g00, gxy);
    w4[1] = make_float4(g11, sc, 0.0f, 0.0f);
}

// ---- kernel 2: map. One block per (b,x); scalar write stream (proven best). --
__global__ __launch_bounds__(256) void map_kernel(
    const float* __restrict__ ws,
    float* __restrict__ out)
{
    const int tid = threadIdx.x;
    const int blk = blockIdx.x;        // blk = b*64 + x
    const int b   = blk >> 6;
    const int x   = blk & 63;

    const int t_idx = tid & 63;
    const int y0    = tid >> 6;        // 0..3

    // wave reads 2 KiB contiguous (L1/L2-resident: 256 KiB total stats)
    const float4* s4 = (const float4*)(ws + ((size_t)((b << 6) | t_idx)) * STATS_F);
    const float4 s0 = s4[0];
    const float4 s1 = s4[1];
    const float mx = s0.x, my = s0.y, g00 = s0.z, gxy = s0.w;
    const float g11 = s1.x, sc = s1.y;

    // fold block-uniform x (same expression order as the verified kernel)
    const float dx = (float)x - mx;
    const float c0 = g00 * dx * dx;
    const float c1 = gxy * dx;

    float* __restrict__ orow = out + ((size_t)blk << 12) + t_idx;

    #pragma unroll
    for (int y = y0; y < MAP_H; y += 4) {
        const float dy  = (float)y - my;
        const float arg = fmaf(dy, fmaf(g11, dy, c1), c0);  // log2-domain quad form
        orow[y << 6] = sc * exp2f(arg);                     // v_exp_f32
    }
}

// ---- fallback: verified single kernel (used if ws too small) ----
__global__ __launch_bounds__(256) void pmap_kernel(
    const void* __restrict__ cp_means_p,
    const void* __restrict__ num_cps_p,
    const void* __restrict__ cp_cov_p,
    float* __restrict__ out)
{
    __shared__ float s_my[T_SIZE], s_g11[T_SIZE], s_c0[T_SIZE], s_c1[T_SIZE], s_sc[T_SIZE];

    const int tid = threadIdx.x;
    const int blk = blockIdx.x;        // blk = b*64 + x
    const int b   = blk >> 6;
    const int x   = blk & 63;

    if (tid < T_SIZE) {
        float mx, my, g00, gxy, g11, sc;
        bezier_stats(cp_means_p, num_cps_p, cp_cov_p, b, tid, mx, my, g00, gxy, g11, sc);
        const float dx = (float)x - mx;
        s_my[tid]  = my;
        s_g11[tid] = g11;
        s_c0[tid]  = g00 * dx * dx;
        s_c1[tid]  = gxy * dx;
        s_sc[tid]  = sc;
    }
    __syncthreads();

    const int t_idx = tid & 63;
    const int y0    = tid >> 6;
    const float my  = s_my[t_idx];
    const float g11 = s_g11[t_idx];
    const float c0  = s_c0[t_idx];
    const float c1  = s_c1[t_idx];
    const float sc  = s_sc[t_idx];

    float* __restrict__ orow = out + ((size_t)blk << 12) + t_idx;

    #pragma unroll
    for (int y = y0; y < MAP_H; y += 4) {
        const float dy  = (float)y - my;
        const float arg = fmaf(dy, fmaf(g11, dy, c1), c0);
        orow[y << 6] = sc * exp2f(arg);
    }
}

extern "C" void kernel_launch(void* const* d_in, const int* in_sizes, int n_in,
                              void* d_out, int out_size, void* d_ws, size_t ws_size,
                              hipStream_t stream) {
    const size_t ws_needed = (size_t)BATCH * T_SIZE * STATS_F * sizeof(float); // 256 KiB
    if (d_ws != nullptr && ws_size >= ws_needed) {
        stats_kernel<<<dim3((BATCH * T_SIZE) / 256), dim3(256), 0, stream>>>(
            d_in[0], d_in[1], d_in[2], (float*)d_ws);
        map_kernel<<<dim3(BATCH * MAP_W), dim3(256), 0, stream>>>(
            (const float*)d_ws, (float*)d_out);
    } else {
        pmap_kernel<<<dim3(BATCH * MAP_W), dim3(256), 0, stream>>>(
            d_in[0], d_in[1], d_in[2], (float*)d_out);
    }
}